// Round 14
// baseline (529.266 us; speedup 1.0000x reference)
//
#include <hip/hip_runtime.h>
#include <math.h>

// N=100000 nodes, E=1600000 edges, F_IN=10 (+2 idx cols), H=128, G=1000 graphs, GAP=3
#define H 128
#define GAPLEN 3
#define DIN 18

static inline int ceil_div(int a, int b){ return (a + b - 1) / b; }

typedef __attribute__((ext_vector_type(8))) short short8;
typedef __attribute__((ext_vector_type(4))) float f32x4;

__device__ __forceinline__ unsigned int bf16pk2(float a, float b){
  unsigned int ua = __float_as_uint(a);
  ua = (ua + 0x7fffu + ((ua >> 16) & 1u)) >> 16;
  unsigned int ub = __float_as_uint(b);
  ub = (ub + 0x7fffu + ((ub >> 16) & 1u)) >> 16;
  return ua | (ub << 16);
}
__device__ __forceinline__ unsigned short bf16r(float x){
  unsigned int u = __float_as_uint(x);
  u = (u + 0x7fffu + ((u >> 16) & 1u)) >> 16;
  return (unsigned short)u;
}
__device__ __forceinline__ float bfu2f(unsigned short h){ return __uint_as_float((unsigned int)h << 16); }
__device__ __forceinline__ float bf16lo(unsigned int u){ return __uint_as_float(u << 16); }
__device__ __forceinline__ float bf16hi(unsigned int u){ return __uint_as_float(u & 0xffff0000u); }

// =================== bucketed CSR build ===================
#define CHUNK 4096

__global__ __launch_bounds__(256) void bhistA_k(const int* __restrict__ ei, int* __restrict__ bh,
                                                int E, int NB){
  __shared__ int lh[1024];
  int t = threadIdx.x;
  for (int j = t; j < 1024; j += 256) lh[j] = 0;
  __syncthreads();
  int base = blockIdx.x * CHUNK;
#pragma unroll
  for (int i = 0; i < 16; ++i){
    int e = base + i * 256 + t;
    if (e < E) atomicAdd(&lh[ei[E + e] >> 7], 1);
  }
  __syncthreads();
  for (int j = t; j < NB; j += 256){
    int v = lh[j];
    if (v) atomicAdd(&bh[j], v);
  }
}

__global__ void bscan_k(const int* __restrict__ bh, int* __restrict__ bbase, int NB){
  __shared__ int sd[1024];
  int t = threadIdx.x;
  int v = (t < NB) ? bh[t] : 0;
  sd[t] = v;
  __syncthreads();
  for (int off = 1; off < 1024; off <<= 1){
    int add = (t >= off) ? sd[t - off] : 0;
    __syncthreads();
    sd[t] += add;
    __syncthreads();
  }
  if (t < NB) bbase[t] = sd[t] - v;
}

__global__ __launch_bounds__(256) void bpartC_k(const int* __restrict__ ei,
                                                const int* __restrict__ bbase,
                                                int* __restrict__ bcur,
                                                int* __restrict__ ebuf, int E, int NB){
  __shared__ int lh[1024];
  __shared__ int lchunk[1024];
  __shared__ int lcur[1024];
  int t = threadIdx.x;
  for (int j = t; j < 1024; j += 256) lh[j] = 0;
  __syncthreads();
  int base = blockIdx.x * CHUNK;
  int pk[16], bk[16];
#pragma unroll
  for (int i = 0; i < 16; ++i){
    int e = base + i * 256 + t;
    if (e < E){
      int s = ei[e];
      int d = ei[E + e];
      bk[i] = d >> 7;
      pk[i] = ((d & 127) << 17) | s;
      atomicAdd(&lh[bk[i]], 1);
    } else bk[i] = -1;
  }
  __syncthreads();
  for (int j = t; j < NB; j += 256){
    int c = lh[j];
    if (c) lchunk[j] = bbase[j] + atomicAdd(&bcur[j], c);
    lcur[j] = 0;
  }
  __syncthreads();
#pragma unroll
  for (int i = 0; i < 16; ++i){
    if (bk[i] >= 0){
      int off = atomicAdd(&lcur[bk[i]], 1);
      ebuf[lchunk[bk[i]] + off] = pk[i];
    }
  }
}

__global__ __launch_bounds__(256) void bbuildD_k(const int* __restrict__ ebuf,
                                                 const int* __restrict__ bh,
                                                 const int* __restrict__ bbase,
                                                 int* __restrict__ rp, int* __restrict__ cnt,
                                                 float* __restrict__ dis, int* __restrict__ csr,
                                                 int n){
  __shared__ int hist[128], sc[128], gb[128], curr[128];
  int b = blockIdx.x;
  int t = threadIdx.x;
  int sb = bbase[b];
  int mb = bh[b];
  if (t < 128) hist[t] = 0;
  __syncthreads();
  for (int i = t; i < mb; i += 256)
    atomicAdd(&hist[ebuf[sb + i] >> 17], 1);
  __syncthreads();
  if (t < 128) sc[t] = hist[t];
  __syncthreads();
  for (int off = 1; off < 128; off <<= 1){
    int add = (t < 128 && t >= off) ? sc[t - off] : 0;
    __syncthreads();
    if (t < 128) sc[t] += add;
    __syncthreads();
  }
  if (t < 128){
    int node = b * 128 + t;
    int rpv = sb + sc[t] - hist[t];
    gb[t] = rpv;
    curr[t] = 0;
    if (node < n){
      rp[node] = rpv;
      cnt[node] = hist[t];
      dis[node] = rsqrtf((float)hist[t] + 1.0f);
    }
  }
  __syncthreads();
  for (int i = t; i < mb; i += 256){
    int p = ebuf[sb + i];
    int dl = p >> 17;
    int src = p & 0x1FFFF;
    int off = atomicAdd(&curr[dl], 1);
    csr[gb[dl] + off] = src;
  }
}

// =================== degree-sorted processing order (prc only) ===================
__global__ void dhist_k(const int* __restrict__ cnt, int* __restrict__ dh, int n){
  __shared__ int lh[256];
  int t = threadIdx.x;
  lh[t] = 0;
  __syncthreads();
  int i = blockIdx.x * 256 + t;
  if (i < n){
    int d = cnt[i]; if (d > 255) d = 255;
    atomicAdd(&lh[d], 1);
  }
  __syncthreads();
  if (lh[t]) atomicAdd(&dh[t], lh[t]);
}

__global__ void dscan_k(const int* __restrict__ dh, int* __restrict__ dbase){
  __shared__ int sd[256];
  int t = threadIdx.x;
  int v = dh[t];
  sd[t] = v;
  __syncthreads();
  for (int off = 1; off < 256; off <<= 1){
    int add = (t >= off) ? sd[t - off] : 0;
    __syncthreads();
    sd[t] += add;
    __syncthreads();
  }
  dbase[t] = sd[t] - v;
}

__global__ void dperm_k(const int* __restrict__ cnt, const int* __restrict__ rp,
                        const float* __restrict__ dis, const int* __restrict__ dbase,
                        int* __restrict__ dcur, int4* __restrict__ prc, int n){
  __shared__ int lh[256], lbase[256], lcur[256];
  int t = threadIdx.x;
  lh[t] = 0;
  __syncthreads();
  int i = blockIdx.x * 256 + t;
  bool ok = i < n;
  int d = 0, db = 0;
  if (ok){
    d = cnt[i]; db = d > 255 ? 255 : d;
    atomicAdd(&lh[db], 1);
  }
  __syncthreads();
  int c = lh[t];
  lcur[t] = 0;
  if (c) lbase[t] = dbase[t] + atomicAdd(&dcur[t], c);
  __syncthreads();
  if (ok){
    int off = atomicAdd(&lcur[db], 1);
    int pos = lbase[db] + off;
    prc[pos] = int4{rp[i], d, i, __float_as_int(dis[i])};
  }
}

// ---------------- feats (pre-scaled by dis) -> BF16 packed [N][9] uints ----------------
__global__ void build_feats_k(const float* __restrict__ x, const float* __restrict__ se,
                              const float* __restrict__ ne, const float* __restrict__ dis,
                              unsigned int* __restrict__ f16, int n){
  int i = blockIdx.x * 256 + threadIdx.x;
  if (i >= n) return;
  const float* xr = x + (size_t)i * 12;
  float di = dis[i];
  float v[18];
#pragma unroll
  for (int c = 0; c < 10; ++c) v[c] = di * xr[c];
  int st = (int)xr[10];
  int nv = (int)xr[11];
#pragma unroll
  for (int c = 0; c < 4; ++c){
    v[10 + c] = di * se[st * 4 + c];
    v[14 + c] = di * ne[nv * 4 + c];
  }
  unsigned int* fr = f16 + (size_t)i * 9;
#pragma unroll
  for (int q = 0; q < 9; ++q) fr[q] = bf16pk2(v[2*q], v[2*q + 1]);
}

// ---------------- agg d=18 on BF16 feats (L2-resident), 16 lanes/node ----------------
__global__ __launch_bounds__(256) void agg18b_k(const unsigned int* __restrict__ fw16,
                                                const int4* __restrict__ prc,
                                                const int* __restrict__ csr,
                                                float* __restrict__ out, int n){
  int i = blockIdx.x * 16 + (threadIdx.x >> 4);
  if (i >= n) return;
  int4 v = prc[i];
  int start = v.x, m = v.y, node = v.z;
  float di = __int_as_float(v.w);
  int lane = threadIdx.x & 15;
  bool act = lane < 9;
  float ax = 0.f, ay = 0.f, bx = 0.f, by = 0.f;
  int e = 0;
  for (; e + 4 <= m; e += 4){
    int s0 = csr[start + e + 0];
    int s1 = csr[start + e + 1];
    int s2 = csr[start + e + 2];
    int s3 = csr[start + e + 3];
    if (act){
      unsigned int u0 = fw16[(size_t)s0 * 9 + lane];
      unsigned int u1 = fw16[(size_t)s1 * 9 + lane];
      unsigned int u2 = fw16[(size_t)s2 * 9 + lane];
      unsigned int u3 = fw16[(size_t)s3 * 9 + lane];
      ax += bf16lo(u0) + bf16lo(u1);  ay += bf16hi(u0) + bf16hi(u1);
      bx += bf16lo(u2) + bf16lo(u3);  by += bf16hi(u2) + bf16hi(u3);
    }
  }
  for (; e < m; ++e){
    int s = csr[start + e];
    if (act){
      unsigned int u = fw16[(size_t)s * 9 + lane];
      ax += bf16lo(u); ay += bf16hi(u);
    }
  }
  if (act){
    unsigned int su = fw16[(size_t)node * 9 + lane];
    float2 o;
    o.x = di * (ax + bx + bf16lo(su));
    o.y = di * (ay + by + bf16hi(su));
    *(float2*)&out[(size_t)node * DIN + lane * 2] = o;
  }
}

// ---------------- agg d=128 on BF16 gather array -> A_hi/A_lo bf16 split ----------------
__global__ __launch_bounds__(256) void agg128b_k(const unsigned int* __restrict__ hw16,
                                                 const int4* __restrict__ prc,
                                                 const int* __restrict__ csr,
                                                 unsigned int* __restrict__ Ahi,
                                                 unsigned int* __restrict__ Alo, int n){
  int i = blockIdx.x * 4 + (threadIdx.x >> 6);
  if (i >= n) return;
  int4 v = prc[i];
  int start = __builtin_amdgcn_readfirstlane(v.x);
  int m     = __builtin_amdgcn_readfirstlane(v.y);
  int node  = __builtin_amdgcn_readfirstlane(v.z);
  float di  = __int_as_float(__builtin_amdgcn_readfirstlane(v.w));
  int l = threadIdx.x & 63;
  const unsigned int* hp = hw16 + l;
  float ax0 = 0.f, ay0 = 0.f, ax1 = 0.f, ay1 = 0.f;
  float ax2 = 0.f, ay2 = 0.f, ax3 = 0.f, ay3 = 0.f;
  int e = 0;
  for (; e + 8 <= m; e += 8){
    int s0 = csr[start + e + 0];
    int s1 = csr[start + e + 1];
    int s2 = csr[start + e + 2];
    int s3 = csr[start + e + 3];
    int s4 = csr[start + e + 4];
    int s5 = csr[start + e + 5];
    int s6 = csr[start + e + 6];
    int s7 = csr[start + e + 7];
    unsigned int u0 = hp[(size_t)s0 << 6];
    unsigned int u1 = hp[(size_t)s1 << 6];
    unsigned int u2 = hp[(size_t)s2 << 6];
    unsigned int u3 = hp[(size_t)s3 << 6];
    unsigned int u4 = hp[(size_t)s4 << 6];
    unsigned int u5 = hp[(size_t)s5 << 6];
    unsigned int u6 = hp[(size_t)s6 << 6];
    unsigned int u7 = hp[(size_t)s7 << 6];
    ax0 += bf16lo(u0) + bf16lo(u1);  ay0 += bf16hi(u0) + bf16hi(u1);
    ax1 += bf16lo(u2) + bf16lo(u3);  ay1 += bf16hi(u2) + bf16hi(u3);
    ax2 += bf16lo(u4) + bf16lo(u5);  ay2 += bf16hi(u4) + bf16hi(u5);
    ax3 += bf16lo(u6) + bf16lo(u7);  ay3 += bf16hi(u6) + bf16hi(u7);
  }
  for (; e < m; ++e){
    int s = csr[start + e];
    unsigned int u = hp[(size_t)s << 6];
    ax0 += bf16lo(u); ay0 += bf16hi(u);
  }
  unsigned int su = hp[(size_t)node << 6];
  float vx = di * (ax0 + ax1 + ax2 + ax3 + bf16lo(su));
  float vy = di * (ay0 + ay1 + ay2 + ay3 + bf16hi(su));
  unsigned short hx = bf16r(vx), hy = bf16r(vy);
  float rx = vx - bfu2f(hx), ry = vy - bfu2f(hy);
  Ahi[(size_t)node * 64 + l] = (unsigned int)hx | ((unsigned int)hy << 16);
  Alo[(size_t)node * 64 + l] = (unsigned int)bf16r(rx) | ((unsigned int)bf16r(ry) << 16);
}

// ---------------- weight transpose + bf16 hi/lo split: WT[c][k] ----------------
__global__ void wcvt_k(const float* __restrict__ W, unsigned short* __restrict__ hi,
                       unsigned short* __restrict__ lo){
  int idx = blockIdx.x * 256 + threadIdx.x;   // 16384 = 128x128
  int k = idx >> 7, c = idx & 127;
  float v = W[idx];   // W[k][c]
  unsigned short h = bf16r(v);
  float r = v - bfu2f(h);
  hi[(size_t)c * 128 + k] = h;
  lo[(size_t)c * 128 + k] = bf16r(r);
}

// ---------------- GEMM: [n,18] @ [18,128] + bias, relu, x dis -> BF16 [n][128] ----------------
__global__ void gemm18_k(const float* __restrict__ A, const float* __restrict__ W,
                         const float* __restrict__ b, const float* __restrict__ dis,
                         unsigned int* __restrict__ C16, int n){
  __shared__ float sw[DIN * H];
  __shared__ float sb[H];
  __shared__ float sa[8][DIN];
  int t = threadIdx.x;
  for (int i = t; i < DIN * H; i += 256) sw[i] = W[i];
  if (t < H) sb[t] = b[t];
  int row0 = blockIdx.x * 8;
  for (int i = t; i < 8 * DIN; i += 256){
    int r = i / DIN, c = i % DIN;
    int rr = row0 + r;
    sa[r][c] = (rr < n) ? A[(size_t)rr * DIN + c] : 0.f;
  }
  __syncthreads();
  int r = t >> 5, lane = t & 31;
  int row = row0 + r;
  if (row >= n) return;
  int c0 = lane * 4;
  float ox = sb[c0], oy = sb[c0 + 1], oz = sb[c0 + 2], ow = sb[c0 + 3];
#pragma unroll
  for (int k = 0; k < DIN; ++k){
    float a = sa[r][k];
    const float4 w = *(const float4*)&sw[k * H + c0];
    ox += a * w.x; oy += a * w.y; oz += a * w.z; ow += a * w.w;
  }
  float di = dis[row];
  uint2 pk;
  pk.x = bf16pk2(di * fmaxf(ox, 0.f), di * fmaxf(oy, 0.f));
  pk.y = bf16pk2(di * fmaxf(oz, 0.f), di * fmaxf(ow, 0.f));
  *(uint2*)&C16[(size_t)row * 64 + lane * 2] = pk;
}

// ---------------- MFMA GEMM: A(hi+lo bf16)[n,128] @ WT(hi+lo) + bias, relu ----------------
template<int OUTMODE>
__global__ __launch_bounds__(256) void gemm128m_k(const unsigned int* __restrict__ Ahi,
                                                  const unsigned int* __restrict__ Alo,
                                                  const unsigned short* __restrict__ BThi,
                                                  const unsigned short* __restrict__ BTlo,
                                                  const float* __restrict__ bias,
                                                  const float* __restrict__ dis,
                                                  float* __restrict__ C,
                                                  unsigned short* __restrict__ C16, int n){
  int t = threadIdx.x;
  int wid = t >> 6, l = t & 63;
  int r = l & 15, g = l >> 4;
  int row0 = blockIdx.x * 128 + wid * 32;
  f32x4 acc[2][8];
#pragma unroll
  for (int rt = 0; rt < 2; ++rt)
#pragma unroll
    for (int ct = 0; ct < 8; ++ct) acc[rt][ct] = f32x4{0.f, 0.f, 0.f, 0.f};

#pragma unroll
  for (int ks = 0; ks < 4; ++ks){
    short8 ah[2], al[2];
#pragma unroll
    for (int rt = 0; rt < 2; ++rt){
      int row = row0 + rt * 16 + r;
      if (row >= n) row = n - 1;
      ah[rt] = *(const short8*)(Ahi + (size_t)row * 64 + ks * 16 + 4 * g);
      al[rt] = *(const short8*)(Alo + (size_t)row * 64 + ks * 16 + 4 * g);
    }
#pragma unroll
    for (int ct = 0; ct < 8; ++ct){
      int c = ct * 16 + r;
      short8 bh = *(const short8*)(BThi + (size_t)c * 128 + ks * 32 + 8 * g);
      short8 bl = *(const short8*)(BTlo + (size_t)c * 128 + ks * 32 + 8 * g);
#pragma unroll
      for (int rt = 0; rt < 2; ++rt){
        acc[rt][ct] = __builtin_amdgcn_mfma_f32_16x16x32_bf16(ah[rt], bh, acc[rt][ct], 0, 0, 0);
        acc[rt][ct] = __builtin_amdgcn_mfma_f32_16x16x32_bf16(al[rt], bh, acc[rt][ct], 0, 0, 0);
        acc[rt][ct] = __builtin_amdgcn_mfma_f32_16x16x32_bf16(ah[rt], bl, acc[rt][ct], 0, 0, 0);
      }
    }
  }
  float bs[8];
#pragma unroll
  for (int ct = 0; ct < 8; ++ct) bs[ct] = bias[ct * 16 + r];
#pragma unroll
  for (int rt = 0; rt < 2; ++rt){
#pragma unroll
    for (int j = 0; j < 4; ++j){
      int row = row0 + rt * 16 + 4 * g + j;
      if (row < n){
        float di = dis[row];
#pragma unroll
        for (int ct = 0; ct < 8; ++ct){
          int col = ct * 16 + r;
          float o = fmaxf(acc[rt][ct][j] + bs[ct], 0.f);
          if (OUTMODE == 0) C16[(size_t)row * 128 + col] = bf16r(di * o);
          else              C[(size_t)row * 128 + col] = o;
        }
      }
    }
  }
}

// ---------------- graph offsets ----------------
__global__ void ghist_k(const int* __restrict__ batch, int* __restrict__ gc, int n){
  int i = blockIdx.x * 256 + threadIdx.x;
  if (i < n) atomicAdd(&gc[batch[i]], 1);
}

__global__ void gscan_k(const int* __restrict__ gc, int* __restrict__ go, int G){
  __shared__ int sd[1024];
  int t = threadIdx.x;
  int v = (t < G) ? gc[t] : 0;
  sd[t] = v;
  __syncthreads();
  for (int off = 1; off < 1024; off <<= 1){
    int add = (t >= off) ? sd[t - off] : 0;
    __syncthreads();
    sd[t] += add;
    __syncthreads();
  }
  if (t < G) go[t] = sd[t] - v;
}

// ---------------- gap gather ----------------
__global__ void gather_k(const float* __restrict__ h3, const int* __restrict__ go,
                         const int* __restrict__ gap,
                         float* __restrict__ inp, float* __restrict__ hf,
                         float* __restrict__ hb, int G){
  int g = blockIdx.x;
  int t = threadIdx.x;
  if (g >= G) return;
  int idx = go[g] + gap[0];
  float v = h3[(size_t)idx * H + t];
  inp[(size_t)g * H + t] = v;
  hf[(size_t)g * H + t] = v;
  hb[(size_t)g * H + t] = v;
}

// ---------------- GRU step: 512 thr, 1 graph per (j,q) thread, 4 graphs/block ----------------
#define GPB 4
__device__ __forceinline__ float sigf(float x){ return 1.f / (1.f + expf(-x)); }

__global__ __launch_bounds__(512) void gru_step_k(
    const float* __restrict__ inp, float* __restrict__ hf, float* __restrict__ hb,
    const float* __restrict__ Wih_f, const float* __restrict__ Whh_f,
    const float* __restrict__ bih_f, const float* __restrict__ bhh_f,
    const float* __restrict__ Wih_b, const float* __restrict__ Whh_b,
    const float* __restrict__ bih_b, const float* __restrict__ bhh_b, int G){
  int cell = blockIdx.y;
  const float* Wih = cell ? Wih_b : Wih_f;
  const float* Whh = cell ? Whh_b : Whh_f;
  const float* bih = cell ? bih_b : bih_f;
  const float* bhh = cell ? bhh_b : bhh_f;
  float* h = cell ? hb : hf;

  __shared__ float sx[GPB][H];
  __shared__ float sh[GPB][H];
  int g0 = blockIdx.x * GPB;
  int t = threadIdx.x;
  for (int i = t; i < GPB * H; i += 512){
    int g = i >> 7, c = i & 127;
    int gg = g0 + g;
    sx[g][c] = (gg < G) ? inp[(size_t)gg * H + c] : 0.f;
    sh[g][c] = (gg < G) ? h[(size_t)gg * H + c] : 0.f;
  }
  __syncthreads();
  int j = t & 127;
  int g = t >> 7;          // one graph per 128-thread slice
  float ir = 0.f, iz = 0.f, in_ = 0.f, hr = 0.f, hz = 0.f, hn = 0.f;
#pragma unroll 4
  for (int k = 0; k < H; ++k){
    const float* wi = Wih + (size_t)k * 384;
    const float* wh = Whh + (size_t)k * 384;
    float xv = sx[g][k];
    float hv = sh[g][k];
    ir += xv * wi[j]; iz += xv * wi[128 + j]; in_ += xv * wi[256 + j];
    hr += hv * wh[j]; hz += hv * wh[128 + j]; hn += hv * wh[256 + j];
  }
  int gg = g0 + g;
  if (gg < G){
    float r = sigf(ir + bih[j] + hr + bhh[j]);
    float z = sigf(iz + bih[128 + j] + hz + bhh[128 + j]);
    float nn = tanhf(in_ + bih[256 + j] + r * (hn + bhh[256 + j]));
    float hv = sh[g][j];
    h[(size_t)gg * H + j] = (1.f - z) * nn + z * hv;
  }
}

// ---------------- post step: 512 thr, 1 graph per (j,q) slice ----------------
__global__ __launch_bounds__(512) void post_step_k(
    const float* __restrict__ hf, const float* __restrict__ hb,
    const float* __restrict__ Wred, const float* __restrict__ bred,
    const float* __restrict__ Wh1, const float* __restrict__ bh1,
    const float* __restrict__ Wh2, const float* __restrict__ bh2,
    float* __restrict__ inp, float* __restrict__ out, int G, int tstep){
  __shared__ float so[GPB][256];
  __shared__ float st1[GPB][H];
  int g0 = blockIdx.x * GPB;
  int t = threadIdx.x;
  for (int i = t; i < GPB * H; i += 512){
    int g = i >> 7, c = i & 127;
    int gg = g0 + g;
    so[g][c]       = (gg < G) ? hf[(size_t)gg * H + c] : 0.f;
    so[g][128 + c] = (gg < G) ? hb[(size_t)gg * H + c] : 0.f;
  }
  __syncthreads();
  int j = t & 127;
  int g = t >> 7;
  float a1 = 0.f, a2 = 0.f;
#pragma unroll 8
  for (int k = 0; k < 256; ++k){
    float w1 = Wh1[(size_t)k * H + j];
    float w2 = Wred[(size_t)k * H + j];
    float o = so[g][k];
    a1 += o * w1;
    a2 += o * w2;
  }
  int gg = g0 + g;
  float t1 = fmaxf(a1 + bh1[j], 0.f);
  st1[g][j] = (gg < G) ? t1 : 0.f;
  if (gg < G) inp[(size_t)gg * H + j] = a2 + bred[j];
  __syncthreads();
  if (t < GPB * 2){
    int gq = t >> 1, o = t & 1;
    int g2 = g0 + gq;
    if (g2 < G){
      float s = bh2[o];
#pragma unroll 8
      for (int k = 0; k < H; ++k) s += st1[gq][k] * Wh2[k * 2 + o];
      out[((size_t)g2 * GAPLEN + tstep) * 2 + o] = s;
    }
  }
}

// =======================================================================
extern "C" void kernel_launch(void* const* d_in, const int* in_sizes, int n_in,
                              void* d_out, int out_size, void* d_ws, size_t ws_size,
                              hipStream_t stream) {
  const float* x     = (const float*)d_in[0];
  const int*   ei    = (const int*)d_in[1];
  const int*   batch = (const int*)d_in[2];
  const float* semb  = (const float*)d_in[3];
  const float* nemb  = (const float*)d_in[4];
  const float* W1 = (const float*)d_in[5];  const float* b1 = (const float*)d_in[6];
  const float* W2 = (const float*)d_in[7];  const float* b2 = (const float*)d_in[8];
  const float* W3 = (const float*)d_in[9];  const float* b3 = (const float*)d_in[10];
  const float* Wih_f = (const float*)d_in[11]; const float* Whh_f = (const float*)d_in[12];
  const float* bih_f = (const float*)d_in[13]; const float* bhh_f = (const float*)d_in[14];
  const float* Wih_b = (const float*)d_in[15]; const float* Whh_b = (const float*)d_in[16];
  const float* bih_b = (const float*)d_in[17]; const float* bhh_b = (const float*)d_in[18];
  const float* Wred = (const float*)d_in[19]; const float* bred = (const float*)d_in[20];
  const float* Wh1  = (const float*)d_in[21]; const float* bh1  = (const float*)d_in[22];
  const float* Wh2  = (const float*)d_in[23]; const float* bh2  = (const float*)d_in[24];
  const int* gap = (const int*)d_in[26];

  int N = in_sizes[0] / 12;
  int E = in_sizes[1] / 2;
  int G = out_size / (GAPLEN * 2);
  int NB = ceil_div(N, 128);
  float* out = (float*)d_out;

  char* ws = (char*)d_ws;
  size_t off = 0;
  auto alloc = [&](size_t bytes) -> void* {
    void* p = ws + off;
    off += (bytes + 511) & ~(size_t)511;
    return p;
  };
  unsigned int* feats16 = (unsigned int*)alloc((size_t)N * 9 * 4);  // bf16 packed [N][9]
  float* agg1   = (float*)alloc((size_t)N * DIN * 4);  // [N][18] fp32
  float* bufA   = (float*)alloc((size_t)N * H * 4);    // fp32 h3
  unsigned int* Ahi = (unsigned int*)alloc((size_t)N * 64 * 4);  // agg out bf16 hi [N][64]
  unsigned int* Alo = (unsigned int*)alloc((size_t)N * 64 * 4);  // agg out bf16 lo
  unsigned int* hb16 = (unsigned int*)alloc((size_t)N * H * 2);  // bf16 gather copy [N][128]
  unsigned short* w2thi = (unsigned short*)alloc(16384 * 2);
  unsigned short* w2tlo = (unsigned short*)alloc(16384 * 2);
  unsigned short* w3thi = (unsigned short*)alloc(16384 * 2);
  unsigned short* w3tlo = (unsigned short*)alloc(16384 * 2);
  int*   cnt    = (int*)alloc((size_t)N * 4);
  float* dis    = (float*)alloc((size_t)N * 4);
  int*   rp     = (int*)alloc((size_t)N * 4);
  int*   csr    = (int*)alloc((size_t)E * 4);
  int*   ebuf   = (int*)alloc((size_t)E * 4);
  int4*  prc    = (int4*)alloc((size_t)N * 16);
  int*   bh     = (int*)alloc((size_t)NB * 4);
  int*   bbase  = (int*)alloc((size_t)NB * 4);
  int*   bcur   = (int*)alloc((size_t)NB * 4);
  int*   dh     = (int*)alloc(256 * 4);
  int*   dbase  = (int*)alloc(256 * 4);
  int*   dcur   = (int*)alloc(256 * 4);
  int*   gc     = (int*)alloc((size_t)G * 4);
  int*   go     = (int*)alloc((size_t)G * 4);
  float* ginp   = (float*)alloc((size_t)G * H * 4);
  float* ghf    = (float*)alloc((size_t)G * H * 4);
  float* ghb    = (float*)alloc((size_t)G * H * 4);
  (void)ws_size; (void)n_in;

  hipMemsetAsync(bh, 0, (size_t)NB * 4, stream);
  hipMemsetAsync(bcur, 0, (size_t)NB * 4, stream);
  hipMemsetAsync(dh, 0, 256 * 4, stream);
  hipMemsetAsync(dcur, 0, 256 * 4, stream);
  hipMemsetAsync(gc, 0, (size_t)G * 4, stream);

  int nb256 = ceil_div(N, 256);
  int ebC   = ceil_div(E, CHUNK);

  // weight transpose+split (independent)
  wcvt_k<<<64, 256, 0, stream>>>(W2, w2thi, w2tlo);
  wcvt_k<<<64, 256, 0, stream>>>(W3, w3thi, w3tlo);

  // CSR build -> degree order (prc) -> bf16 scaled feats
  bhistA_k<<<ebC, 256, 0, stream>>>(ei, bh, E, NB);
  bscan_k<<<1, 1024, 0, stream>>>(bh, bbase, NB);
  bpartC_k<<<ebC, 256, 0, stream>>>(ei, bbase, bcur, ebuf, E, NB);
  bbuildD_k<<<NB, 256, 0, stream>>>(ebuf, bh, bbase, rp, cnt, dis, csr, N);
  dhist_k<<<nb256, 256, 0, stream>>>(cnt, dh, N);
  dscan_k<<<1, 256, 0, stream>>>(dh, dbase);
  dperm_k<<<nb256, 256, 0, stream>>>(cnt, rp, dis, dbase, dcur, prc, N);
  build_feats_k<<<nb256, 256, 0, stream>>>(x, semb, nemb, dis, feats16, N);

  int gemmb = ceil_div(N, 128);

  // layer 1: agg18 on bf16 -> gemm18 -> hb16
  agg18b_k<<<ceil_div(N, 16), 256, 0, stream>>>(feats16, prc, csr, agg1, N);
  gemm18_k<<<ceil_div(N, 8), 256, 0, stream>>>(agg1, W1, b1, dis, hb16, N);
  // layer 2: bf16 gather -> A_hi/A_lo -> MFMA gemm -> hb16
  agg128b_k<<<ceil_div(N, 4), 256, 0, stream>>>(hb16, prc, csr, Ahi, Alo, N);
  gemm128m_k<0><<<gemmb, 256, 0, stream>>>(Ahi, Alo, w2thi, w2tlo, b2, dis,
                                           nullptr, (unsigned short*)hb16, N);
  // layer 3: bf16 gather -> A_hi/A_lo -> MFMA gemm -> fp32 h3
  agg128b_k<<<ceil_div(N, 4), 256, 0, stream>>>(hb16, prc, csr, Ahi, Alo, N);
  gemm128m_k<1><<<gemmb, 256, 0, stream>>>(Ahi, Alo, w3thi, w3tlo, b3, dis,
                                           bufA, nullptr, N);   // bufA = h3

  // graph offsets + decoder
  ghist_k<<<nb256, 256, 0, stream>>>(batch, gc, N);
  gscan_k<<<1, 1024, 0, stream>>>(gc, go, G);
  gather_k<<<G, H, 0, stream>>>(bufA, go, gap, ginp, ghf, ghb, G);

  int gb = ceil_div(G, GPB);
  for (int t = 0; t < GAPLEN; ++t){
    gru_step_k<<<dim3(gb, 2), 512, 0, stream>>>(ginp, ghf, ghb,
                                                Wih_f, Whh_f, bih_f, bhh_f,
                                                Wih_b, Whh_b, bih_b, bhh_b, G);
    post_step_k<<<gb, 512, 0, stream>>>(ghf, ghb, Wred, bred, Wh1, bh1, Wh2, bh2,
                                        ginp, out, G, t);
  }
}

// Round 15
// 506.041 us; speedup vs baseline: 1.0459x; 1.0459x over previous
//
#include <hip/hip_runtime.h>
#include <math.h>

// N=100000 nodes, E=1600000 edges, F_IN=10 (+2 idx cols), H=128, G=1000 graphs, GAP=3
#define H 128
#define GAPLEN 3
#define DIN 18

static inline int ceil_div(int a, int b){ return (a + b - 1) / b; }

typedef __attribute__((ext_vector_type(8))) short short8;
typedef __attribute__((ext_vector_type(4))) float f32x4;

__device__ __forceinline__ unsigned int bf16pk2(float a, float b){
  unsigned int ua = __float_as_uint(a);
  ua = (ua + 0x7fffu + ((ua >> 16) & 1u)) >> 16;
  unsigned int ub = __float_as_uint(b);
  ub = (ub + 0x7fffu + ((ub >> 16) & 1u)) >> 16;
  return ua | (ub << 16);
}
__device__ __forceinline__ unsigned short bf16r(float x){
  unsigned int u = __float_as_uint(x);
  u = (u + 0x7fffu + ((u >> 16) & 1u)) >> 16;
  return (unsigned short)u;
}
__device__ __forceinline__ float bfu2f(unsigned short h){ return __uint_as_float((unsigned int)h << 16); }
__device__ __forceinline__ float bf16lo(unsigned int u){ return __uint_as_float(u << 16); }
__device__ __forceinline__ float bf16hi(unsigned int u){ return __uint_as_float(u & 0xffff0000u); }

// =================== bucketed CSR build ===================
#define CHUNK 4096

__global__ __launch_bounds__(256) void bhistA_k(const int* __restrict__ ei, int* __restrict__ bh,
                                                int E, int NB){
  __shared__ int lh[1024];
  int t = threadIdx.x;
  for (int j = t; j < 1024; j += 256) lh[j] = 0;
  __syncthreads();
  int base = blockIdx.x * CHUNK;
#pragma unroll
  for (int i = 0; i < 16; ++i){
    int e = base + i * 256 + t;
    if (e < E) atomicAdd(&lh[ei[E + e] >> 7], 1);
  }
  __syncthreads();
  for (int j = t; j < NB; j += 256){
    int v = lh[j];
    if (v) atomicAdd(&bh[j], v);
  }
}

__global__ void bscan_k(const int* __restrict__ bh, int* __restrict__ bbase, int NB){
  __shared__ int sd[1024];
  int t = threadIdx.x;
  int v = (t < NB) ? bh[t] : 0;
  sd[t] = v;
  __syncthreads();
  for (int off = 1; off < 1024; off <<= 1){
    int add = (t >= off) ? sd[t - off] : 0;
    __syncthreads();
    sd[t] += add;
    __syncthreads();
  }
  if (t < NB) bbase[t] = sd[t] - v;
}

__global__ __launch_bounds__(256) void bpartC_k(const int* __restrict__ ei,
                                                const int* __restrict__ bbase,
                                                int* __restrict__ bcur,
                                                int* __restrict__ ebuf, int E, int NB){
  __shared__ int lh[1024];
  __shared__ int lchunk[1024];
  __shared__ int lcur[1024];
  int t = threadIdx.x;
  for (int j = t; j < 1024; j += 256) lh[j] = 0;
  __syncthreads();
  int base = blockIdx.x * CHUNK;
  int pk[16], bk[16];
#pragma unroll
  for (int i = 0; i < 16; ++i){
    int e = base + i * 256 + t;
    if (e < E){
      int s = ei[e];
      int d = ei[E + e];
      bk[i] = d >> 7;
      pk[i] = ((d & 127) << 17) | s;
      atomicAdd(&lh[bk[i]], 1);
    } else bk[i] = -1;
  }
  __syncthreads();
  for (int j = t; j < NB; j += 256){
    int c = lh[j];
    if (c) lchunk[j] = bbase[j] + atomicAdd(&bcur[j], c);
    lcur[j] = 0;
  }
  __syncthreads();
#pragma unroll
  for (int i = 0; i < 16; ++i){
    if (bk[i] >= 0){
      int off = atomicAdd(&lcur[bk[i]], 1);
      ebuf[lchunk[bk[i]] + off] = pk[i];
    }
  }
}

__global__ __launch_bounds__(256) void bbuildD_k(const int* __restrict__ ebuf,
                                                 const int* __restrict__ bh,
                                                 const int* __restrict__ bbase,
                                                 int* __restrict__ rp, int* __restrict__ cnt,
                                                 float* __restrict__ dis, int* __restrict__ csr,
                                                 int n){
  __shared__ int hist[128], sc[128], gb[128], curr[128];
  int b = blockIdx.x;
  int t = threadIdx.x;
  int sb = bbase[b];
  int mb = bh[b];
  if (t < 128) hist[t] = 0;
  __syncthreads();
  for (int i = t; i < mb; i += 256)
    atomicAdd(&hist[ebuf[sb + i] >> 17], 1);
  __syncthreads();
  if (t < 128) sc[t] = hist[t];
  __syncthreads();
  for (int off = 1; off < 128; off <<= 1){
    int add = (t < 128 && t >= off) ? sc[t - off] : 0;
    __syncthreads();
    if (t < 128) sc[t] += add;
    __syncthreads();
  }
  if (t < 128){
    int node = b * 128 + t;
    int rpv = sb + sc[t] - hist[t];
    gb[t] = rpv;
    curr[t] = 0;
    if (node < n){
      rp[node] = rpv;
      cnt[node] = hist[t];
      dis[node] = rsqrtf((float)hist[t] + 1.0f);
    }
  }
  __syncthreads();
  for (int i = t; i < mb; i += 256){
    int p = ebuf[sb + i];
    int dl = p >> 17;
    int src = p & 0x1FFFF;
    int off = atomicAdd(&curr[dl], 1);
    csr[gb[dl] + off] = src;
  }
}

// =================== degree-sorted processing order (prc only) ===================
__global__ void dhist_k(const int* __restrict__ cnt, int* __restrict__ dh, int n){
  __shared__ int lh[256];
  int t = threadIdx.x;
  lh[t] = 0;
  __syncthreads();
  int i = blockIdx.x * 256 + t;
  if (i < n){
    int d = cnt[i]; if (d > 255) d = 255;
    atomicAdd(&lh[d], 1);
  }
  __syncthreads();
  if (lh[t]) atomicAdd(&dh[t], lh[t]);
}

__global__ void dscan_k(const int* __restrict__ dh, int* __restrict__ dbase){
  __shared__ int sd[256];
  int t = threadIdx.x;
  int v = dh[t];
  sd[t] = v;
  __syncthreads();
  for (int off = 1; off < 256; off <<= 1){
    int add = (t >= off) ? sd[t - off] : 0;
    __syncthreads();
    sd[t] += add;
    __syncthreads();
  }
  dbase[t] = sd[t] - v;
}

__global__ void dperm_k(const int* __restrict__ cnt, const int* __restrict__ rp,
                        const float* __restrict__ dis, const int* __restrict__ dbase,
                        int* __restrict__ dcur, int4* __restrict__ prc, int n){
  __shared__ int lh[256], lbase[256], lcur[256];
  int t = threadIdx.x;
  lh[t] = 0;
  __syncthreads();
  int i = blockIdx.x * 256 + t;
  bool ok = i < n;
  int d = 0, db = 0;
  if (ok){
    d = cnt[i]; db = d > 255 ? 255 : d;
    atomicAdd(&lh[db], 1);
  }
  __syncthreads();
  int c = lh[t];
  lcur[t] = 0;
  if (c) lbase[t] = dbase[t] + atomicAdd(&dcur[t], c);
  __syncthreads();
  if (ok){
    int off = atomicAdd(&lcur[db], 1);
    int pos = lbase[db] + off;
    prc[pos] = int4{rp[i], d, i, __float_as_int(dis[i])};
  }
}

// ---------------- feats (pre-scaled by dis) -> BF16 packed [N][9] uints ----------------
__global__ void build_feats_k(const float* __restrict__ x, const float* __restrict__ se,
                              const float* __restrict__ ne, const float* __restrict__ dis,
                              unsigned int* __restrict__ f16, int n){
  int i = blockIdx.x * 256 + threadIdx.x;
  if (i >= n) return;
  const float* xr = x + (size_t)i * 12;
  float di = dis[i];
  float v[18];
#pragma unroll
  for (int c = 0; c < 10; ++c) v[c] = di * xr[c];
  int st = (int)xr[10];
  int nv = (int)xr[11];
#pragma unroll
  for (int c = 0; c < 4; ++c){
    v[10 + c] = di * se[st * 4 + c];
    v[14 + c] = di * ne[nv * 4 + c];
  }
  unsigned int* fr = f16 + (size_t)i * 9;
#pragma unroll
  for (int q = 0; q < 9; ++q) fr[q] = bf16pk2(v[2*q], v[2*q + 1]);
}

// ---------------- agg d=18 on BF16 feats (L2-resident), 16 lanes/node ----------------
__global__ __launch_bounds__(256) void agg18b_k(const unsigned int* __restrict__ fw16,
                                                const int4* __restrict__ prc,
                                                const int* __restrict__ csr,
                                                float* __restrict__ out, int n){
  int i = blockIdx.x * 16 + (threadIdx.x >> 4);
  if (i >= n) return;
  int4 v = prc[i];
  int start = v.x, m = v.y, node = v.z;
  float di = __int_as_float(v.w);
  int lane = threadIdx.x & 15;
  bool act = lane < 9;
  float ax = 0.f, ay = 0.f, bx = 0.f, by = 0.f;
  int e = 0;
  for (; e + 4 <= m; e += 4){
    int s0 = csr[start + e + 0];
    int s1 = csr[start + e + 1];
    int s2 = csr[start + e + 2];
    int s3 = csr[start + e + 3];
    if (act){
      unsigned int u0 = fw16[(size_t)s0 * 9 + lane];
      unsigned int u1 = fw16[(size_t)s1 * 9 + lane];
      unsigned int u2 = fw16[(size_t)s2 * 9 + lane];
      unsigned int u3 = fw16[(size_t)s3 * 9 + lane];
      ax += bf16lo(u0) + bf16lo(u1);  ay += bf16hi(u0) + bf16hi(u1);
      bx += bf16lo(u2) + bf16lo(u3);  by += bf16hi(u2) + bf16hi(u3);
    }
  }
  for (; e < m; ++e){
    int s = csr[start + e];
    if (act){
      unsigned int u = fw16[(size_t)s * 9 + lane];
      ax += bf16lo(u); ay += bf16hi(u);
    }
  }
  if (act){
    unsigned int su = fw16[(size_t)node * 9 + lane];
    float2 o;
    o.x = di * (ax + bx + bf16lo(su));
    o.y = di * (ay + by + bf16hi(su));
    *(float2*)&out[(size_t)node * DIN + lane * 2] = o;
  }
}

// ---------------- agg d=128 on BF16 gather array -> A_hi/A_lo bf16 split ----------------
__global__ __launch_bounds__(256) void agg128b_k(const unsigned int* __restrict__ hw16,
                                                 const int4* __restrict__ prc,
                                                 const int* __restrict__ csr,
                                                 unsigned int* __restrict__ Ahi,
                                                 unsigned int* __restrict__ Alo, int n){
  int i = blockIdx.x * 4 + (threadIdx.x >> 6);
  if (i >= n) return;
  int4 v = prc[i];
  int start = __builtin_amdgcn_readfirstlane(v.x);
  int m     = __builtin_amdgcn_readfirstlane(v.y);
  int node  = __builtin_amdgcn_readfirstlane(v.z);
  float di  = __int_as_float(__builtin_amdgcn_readfirstlane(v.w));
  int l = threadIdx.x & 63;
  const unsigned int* hp = hw16 + l;
  float ax0 = 0.f, ay0 = 0.f, ax1 = 0.f, ay1 = 0.f;
  float ax2 = 0.f, ay2 = 0.f, ax3 = 0.f, ay3 = 0.f;
  int e = 0;
  for (; e + 8 <= m; e += 8){
    int s0 = csr[start + e + 0];
    int s1 = csr[start + e + 1];
    int s2 = csr[start + e + 2];
    int s3 = csr[start + e + 3];
    int s4 = csr[start + e + 4];
    int s5 = csr[start + e + 5];
    int s6 = csr[start + e + 6];
    int s7 = csr[start + e + 7];
    unsigned int u0 = hp[(size_t)s0 << 6];
    unsigned int u1 = hp[(size_t)s1 << 6];
    unsigned int u2 = hp[(size_t)s2 << 6];
    unsigned int u3 = hp[(size_t)s3 << 6];
    unsigned int u4 = hp[(size_t)s4 << 6];
    unsigned int u5 = hp[(size_t)s5 << 6];
    unsigned int u6 = hp[(size_t)s6 << 6];
    unsigned int u7 = hp[(size_t)s7 << 6];
    ax0 += bf16lo(u0) + bf16lo(u1);  ay0 += bf16hi(u0) + bf16hi(u1);
    ax1 += bf16lo(u2) + bf16lo(u3);  ay1 += bf16hi(u2) + bf16hi(u3);
    ax2 += bf16lo(u4) + bf16lo(u5);  ay2 += bf16hi(u4) + bf16hi(u5);
    ax3 += bf16lo(u6) + bf16lo(u7);  ay3 += bf16hi(u6) + bf16hi(u7);
  }
  for (; e < m; ++e){
    int s = csr[start + e];
    unsigned int u = hp[(size_t)s << 6];
    ax0 += bf16lo(u); ay0 += bf16hi(u);
  }
  unsigned int su = hp[(size_t)node << 6];
  float vx = di * (ax0 + ax1 + ax2 + ax3 + bf16lo(su));
  float vy = di * (ay0 + ay1 + ay2 + ay3 + bf16hi(su));
  unsigned short hx = bf16r(vx), hy = bf16r(vy);
  float rx = vx - bfu2f(hx), ry = vy - bfu2f(hy);
  Ahi[(size_t)node * 64 + l] = (unsigned int)hx | ((unsigned int)hy << 16);
  Alo[(size_t)node * 64 + l] = (unsigned int)bf16r(rx) | ((unsigned int)bf16r(ry) << 16);
}

// ---------------- weight transpose + bf16 hi/lo split: WT[c][k] ----------------
__global__ void wcvt_k(const float* __restrict__ W, unsigned short* __restrict__ hi,
                       unsigned short* __restrict__ lo){
  int idx = blockIdx.x * 256 + threadIdx.x;   // 16384 = 128x128
  int k = idx >> 7, c = idx & 127;
  float v = W[idx];   // W[k][c]
  unsigned short h = bf16r(v);
  float r = v - bfu2f(h);
  hi[(size_t)c * 128 + k] = h;
  lo[(size_t)c * 128 + k] = bf16r(r);
}

// ---------------- GEMM: [n,18] @ [18,128] + bias, relu, x dis -> BF16 [n][128] ----------------
__global__ void gemm18_k(const float* __restrict__ A, const float* __restrict__ W,
                         const float* __restrict__ b, const float* __restrict__ dis,
                         unsigned int* __restrict__ C16, int n){
  __shared__ float sw[DIN * H];
  __shared__ float sb[H];
  __shared__ float sa[8][DIN];
  int t = threadIdx.x;
  for (int i = t; i < DIN * H; i += 256) sw[i] = W[i];
  if (t < H) sb[t] = b[t];
  int row0 = blockIdx.x * 8;
  for (int i = t; i < 8 * DIN; i += 256){
    int r = i / DIN, c = i % DIN;
    int rr = row0 + r;
    sa[r][c] = (rr < n) ? A[(size_t)rr * DIN + c] : 0.f;
  }
  __syncthreads();
  int r = t >> 5, lane = t & 31;
  int row = row0 + r;
  if (row >= n) return;
  int c0 = lane * 4;
  float ox = sb[c0], oy = sb[c0 + 1], oz = sb[c0 + 2], ow = sb[c0 + 3];
#pragma unroll
  for (int k = 0; k < DIN; ++k){
    float a = sa[r][k];
    const float4 w = *(const float4*)&sw[k * H + c0];
    ox += a * w.x; oy += a * w.y; oz += a * w.z; ow += a * w.w;
  }
  float di = dis[row];
  uint2 pk;
  pk.x = bf16pk2(di * fmaxf(ox, 0.f), di * fmaxf(oy, 0.f));
  pk.y = bf16pk2(di * fmaxf(oz, 0.f), di * fmaxf(ow, 0.f));
  *(uint2*)&C16[(size_t)row * 64 + lane * 2] = pk;
}

// ---------------- MFMA GEMM: A(hi+lo bf16)[n,128] @ WT(hi+lo) + bias, relu ----------------
template<int OUTMODE>
__global__ __launch_bounds__(256) void gemm128m_k(const unsigned int* __restrict__ Ahi,
                                                  const unsigned int* __restrict__ Alo,
                                                  const unsigned short* __restrict__ BThi,
                                                  const unsigned short* __restrict__ BTlo,
                                                  const float* __restrict__ bias,
                                                  const float* __restrict__ dis,
                                                  float* __restrict__ C,
                                                  unsigned short* __restrict__ C16, int n){
  int t = threadIdx.x;
  int wid = t >> 6, l = t & 63;
  int r = l & 15, g = l >> 4;
  int row0 = blockIdx.x * 128 + wid * 32;
  f32x4 acc[2][8];
#pragma unroll
  for (int rt = 0; rt < 2; ++rt)
#pragma unroll
    for (int ct = 0; ct < 8; ++ct) acc[rt][ct] = f32x4{0.f, 0.f, 0.f, 0.f};

#pragma unroll
  for (int ks = 0; ks < 4; ++ks){
    short8 ah[2], al[2];
#pragma unroll
    for (int rt = 0; rt < 2; ++rt){
      int row = row0 + rt * 16 + r;
      if (row >= n) row = n - 1;
      ah[rt] = *(const short8*)(Ahi + (size_t)row * 64 + ks * 16 + 4 * g);
      al[rt] = *(const short8*)(Alo + (size_t)row * 64 + ks * 16 + 4 * g);
    }
#pragma unroll
    for (int ct = 0; ct < 8; ++ct){
      int c = ct * 16 + r;
      short8 bh = *(const short8*)(BThi + (size_t)c * 128 + ks * 32 + 8 * g);
      short8 bl = *(const short8*)(BTlo + (size_t)c * 128 + ks * 32 + 8 * g);
#pragma unroll
      for (int rt = 0; rt < 2; ++rt){
        acc[rt][ct] = __builtin_amdgcn_mfma_f32_16x16x32_bf16(ah[rt], bh, acc[rt][ct], 0, 0, 0);
        acc[rt][ct] = __builtin_amdgcn_mfma_f32_16x16x32_bf16(al[rt], bh, acc[rt][ct], 0, 0, 0);
        acc[rt][ct] = __builtin_amdgcn_mfma_f32_16x16x32_bf16(ah[rt], bl, acc[rt][ct], 0, 0, 0);
      }
    }
  }
  float bs[8];
#pragma unroll
  for (int ct = 0; ct < 8; ++ct) bs[ct] = bias[ct * 16 + r];
#pragma unroll
  for (int rt = 0; rt < 2; ++rt){
#pragma unroll
    for (int j = 0; j < 4; ++j){
      int row = row0 + rt * 16 + 4 * g + j;
      if (row < n){
        float di = dis[row];
#pragma unroll
        for (int ct = 0; ct < 8; ++ct){
          int col = ct * 16 + r;
          float o = fmaxf(acc[rt][ct][j] + bs[ct], 0.f);
          if (OUTMODE == 0) C16[(size_t)row * 128 + col] = bf16r(di * o);
          else              C[(size_t)row * 128 + col] = o;
        }
      }
    }
  }
}

// ---------------- graph offsets ----------------
__global__ void ghist_k(const int* __restrict__ batch, int* __restrict__ gc, int n){
  int i = blockIdx.x * 256 + threadIdx.x;
  if (i < n) atomicAdd(&gc[batch[i]], 1);
}

__global__ void gscan_k(const int* __restrict__ gc, int* __restrict__ go, int G){
  __shared__ int sd[1024];
  int t = threadIdx.x;
  int v = (t < G) ? gc[t] : 0;
  sd[t] = v;
  __syncthreads();
  for (int off = 1; off < 1024; off <<= 1){
    int add = (t >= off) ? sd[t - off] : 0;
    __syncthreads();
    sd[t] += add;
    __syncthreads();
  }
  if (t < G) go[t] = sd[t] - v;
}

// ---------------- gap gather ----------------
__global__ void gather_k(const float* __restrict__ h3, const int* __restrict__ go,
                         const int* __restrict__ gap,
                         float* __restrict__ inp, float* __restrict__ hf,
                         float* __restrict__ hb, int G){
  int g = blockIdx.x;
  int t = threadIdx.x;
  if (g >= G) return;
  int idx = go[g] + gap[0];
  float v = h3[(size_t)idx * H + t];
  inp[(size_t)g * H + t] = v;
  hf[(size_t)g * H + t] = v;
  hb[(size_t)g * H + t] = v;
}

// ---------------- GRU step (round-13 best: 256 thr, 2 graphs/thread, 4 graphs/block) ----------------
#define GPB 4
__device__ __forceinline__ float sigf(float x){ return 1.f / (1.f + expf(-x)); }

__global__ __launch_bounds__(256) void gru_step_k(
    const float* __restrict__ inp, float* __restrict__ hf, float* __restrict__ hb,
    const float* __restrict__ Wih_f, const float* __restrict__ Whh_f,
    const float* __restrict__ bih_f, const float* __restrict__ bhh_f,
    const float* __restrict__ Wih_b, const float* __restrict__ Whh_b,
    const float* __restrict__ bih_b, const float* __restrict__ bhh_b, int G){
  int cell = blockIdx.y;
  const float* Wih = cell ? Wih_b : Wih_f;
  const float* Whh = cell ? Whh_b : Whh_f;
  const float* bih = cell ? bih_b : bih_f;
  const float* bhh = cell ? bhh_b : bhh_f;
  float* h = cell ? hb : hf;

  __shared__ float sx[GPB][H];
  __shared__ float sh[GPB][H];
  int g0 = blockIdx.x * GPB;
  int t = threadIdx.x;
  for (int i = t; i < GPB * H; i += 256){
    int g = i >> 7, c = i & 127;
    int gg = g0 + g;
    sx[g][c] = (gg < G) ? inp[(size_t)gg * H + c] : 0.f;
    sh[g][c] = (gg < G) ? h[(size_t)gg * H + c] : 0.f;
  }
  __syncthreads();
  int j = t & 127;
  int gs = (t >> 7) * 2;
  float ir[2] = {0,0}, iz[2] = {0,0}, in_[2] = {0,0};
  float hr[2] = {0,0}, hz[2] = {0,0}, hn[2] = {0,0};
#pragma unroll 4
  for (int k = 0; k < H; ++k){
    const float* wi = Wih + (size_t)k * 384;
    const float* wh = Whh + (size_t)k * 384;
    float wr = wi[j], wz = wi[128 + j], wn = wi[256 + j];
    float ur = wh[j], uz = wh[128 + j], un = wh[256 + j];
#pragma unroll
    for (int g = 0; g < 2; ++g){
      float xv = sx[gs + g][k];
      float hv = sh[gs + g][k];
      ir[g] += xv * wr; iz[g] += xv * wz; in_[g] += xv * wn;
      hr[g] += hv * ur; hz[g] += hv * uz; hn[g] += hv * un;
    }
  }
  float bir = bih[j], biz = bih[128 + j], bin = bih[256 + j];
  float bhr = bhh[j], bhz = bhh[128 + j], bhn = bhh[256 + j];
#pragma unroll
  for (int g = 0; g < 2; ++g){
    int gg = g0 + gs + g;
    if (gg < G){
      float r = sigf(ir[g] + bir + hr[g] + bhr);
      float z = sigf(iz[g] + biz + hz[g] + bhz);
      float nn = tanhf(in_[g] + bin + r * (hn[g] + bhn));
      float hv = sh[gs + g][j];
      h[(size_t)gg * H + j] = (1.f - z) * nn + z * hv;
    }
  }
}

// ---------------- post step (round-13 best: 256 thr, 2 graphs/thread) ----------------
__global__ __launch_bounds__(256) void post_step_k(
    const float* __restrict__ hf, const float* __restrict__ hb,
    const float* __restrict__ Wred, const float* __restrict__ bred,
    const float* __restrict__ Wh1, const float* __restrict__ bh1,
    const float* __restrict__ Wh2, const float* __restrict__ bh2,
    float* __restrict__ inp, float* __restrict__ out, int G, int tstep){
  __shared__ float so[GPB][256];
  __shared__ float st1[GPB][H];
  int g0 = blockIdx.x * GPB;
  int t = threadIdx.x;
  for (int i = t; i < GPB * H; i += 256){
    int g = i >> 7, c = i & 127;
    int gg = g0 + g;
    so[g][c]       = (gg < G) ? hf[(size_t)gg * H + c] : 0.f;
    so[g][128 + c] = (gg < G) ? hb[(size_t)gg * H + c] : 0.f;
  }
  __syncthreads();
  int j = t & 127;
  int gs = (t >> 7) * 2;
  float a1[2] = {0,0}, a2[2] = {0,0};
#pragma unroll 8
  for (int k = 0; k < 256; ++k){
    float w1 = Wh1[(size_t)k * H + j];
    float w2 = Wred[(size_t)k * H + j];
#pragma unroll
    for (int g = 0; g < 2; ++g){
      float o = so[gs + g][k];
      a1[g] += o * w1;
      a2[g] += o * w2;
    }
  }
  float B1 = bh1[j], BR = bred[j];
#pragma unroll
  for (int g = 0; g < 2; ++g){
    int gg = g0 + gs + g;
    float t1 = fmaxf(a1[g] + B1, 0.f);
    st1[gs + g][j] = (gg < G) ? t1 : 0.f;
    if (gg < G) inp[(size_t)gg * H + j] = a2[g] + BR;
  }
  __syncthreads();
  if (t < GPB * 2){
    int g = t >> 1, o = t & 1;
    int gg = g0 + g;
    if (gg < G){
      float s = bh2[o];
#pragma unroll 8
      for (int k = 0; k < H; ++k) s += st1[g][k] * Wh2[k * 2 + o];
      out[((size_t)gg * GAPLEN + tstep) * 2 + o] = s;
    }
  }
}

// =======================================================================
extern "C" void kernel_launch(void* const* d_in, const int* in_sizes, int n_in,
                              void* d_out, int out_size, void* d_ws, size_t ws_size,
                              hipStream_t stream) {
  const float* x     = (const float*)d_in[0];
  const int*   ei    = (const int*)d_in[1];
  const int*   batch = (const int*)d_in[2];
  const float* semb  = (const float*)d_in[3];
  const float* nemb  = (const float*)d_in[4];
  const float* W1 = (const float*)d_in[5];  const float* b1 = (const float*)d_in[6];
  const float* W2 = (const float*)d_in[7];  const float* b2 = (const float*)d_in[8];
  const float* W3 = (const float*)d_in[9];  const float* b3 = (const float*)d_in[10];
  const float* Wih_f = (const float*)d_in[11]; const float* Whh_f = (const float*)d_in[12];
  const float* bih_f = (const float*)d_in[13]; const float* bhh_f = (const float*)d_in[14];
  const float* Wih_b = (const float*)d_in[15]; const float* Whh_b = (const float*)d_in[16];
  const float* bih_b = (const float*)d_in[17]; const float* bhh_b = (const float*)d_in[18];
  const float* Wred = (const float*)d_in[19]; const float* bred = (const float*)d_in[20];
  const float* Wh1  = (const float*)d_in[21]; const float* bh1  = (const float*)d_in[22];
  const float* Wh2  = (const float*)d_in[23]; const float* bh2  = (const float*)d_in[24];
  const int* gap = (const int*)d_in[26];

  int N = in_sizes[0] / 12;
  int E = in_sizes[1] / 2;
  int G = out_size / (GAPLEN * 2);
  int NB = ceil_div(N, 128);
  float* out = (float*)d_out;

  char* ws = (char*)d_ws;
  size_t off = 0;
  auto alloc = [&](size_t bytes) -> void* {
    void* p = ws + off;
    off += (bytes + 511) & ~(size_t)511;
    return p;
  };
  unsigned int* feats16 = (unsigned int*)alloc((size_t)N * 9 * 4);  // bf16 packed [N][9]
  float* agg1   = (float*)alloc((size_t)N * DIN * 4);  // [N][18] fp32
  float* bufA   = (float*)alloc((size_t)N * H * 4);    // fp32 h3
  unsigned int* Ahi = (unsigned int*)alloc((size_t)N * 64 * 4);  // agg out bf16 hi [N][64]
  unsigned int* Alo = (unsigned int*)alloc((size_t)N * 64 * 4);  // agg out bf16 lo
  unsigned int* hb16 = (unsigned int*)alloc((size_t)N * H * 2);  // bf16 gather copy [N][128]
  unsigned short* w2thi = (unsigned short*)alloc(16384 * 2);
  unsigned short* w2tlo = (unsigned short*)alloc(16384 * 2);
  unsigned short* w3thi = (unsigned short*)alloc(16384 * 2);
  unsigned short* w3tlo = (unsigned short*)alloc(16384 * 2);
  int*   cnt    = (int*)alloc((size_t)N * 4);
  float* dis    = (float*)alloc((size_t)N * 4);
  int*   rp     = (int*)alloc((size_t)N * 4);
  int*   csr    = (int*)alloc((size_t)E * 4);
  int*   ebuf   = (int*)alloc((size_t)E * 4);
  int4*  prc    = (int4*)alloc((size_t)N * 16);
  int*   bh     = (int*)alloc((size_t)NB * 4);
  int*   bbase  = (int*)alloc((size_t)NB * 4);
  int*   bcur   = (int*)alloc((size_t)NB * 4);
  int*   dh     = (int*)alloc(256 * 4);
  int*   dbase  = (int*)alloc(256 * 4);
  int*   dcur   = (int*)alloc(256 * 4);
  int*   gc     = (int*)alloc((size_t)G * 4);
  int*   go     = (int*)alloc((size_t)G * 4);
  float* ginp   = (float*)alloc((size_t)G * H * 4);
  float* ghf    = (float*)alloc((size_t)G * H * 4);
  float* ghb    = (float*)alloc((size_t)G * H * 4);
  (void)ws_size; (void)n_in;

  hipMemsetAsync(bh, 0, (size_t)NB * 4, stream);
  hipMemsetAsync(bcur, 0, (size_t)NB * 4, stream);
  hipMemsetAsync(dh, 0, 256 * 4, stream);
  hipMemsetAsync(dcur, 0, 256 * 4, stream);
  hipMemsetAsync(gc, 0, (size_t)G * 4, stream);

  int nb256 = ceil_div(N, 256);
  int ebC   = ceil_div(E, CHUNK);

  // weight transpose+split (independent)
  wcvt_k<<<64, 256, 0, stream>>>(W2, w2thi, w2tlo);
  wcvt_k<<<64, 256, 0, stream>>>(W3, w3thi, w3tlo);

  // CSR build -> degree order (prc) -> bf16 scaled feats
  bhistA_k<<<ebC, 256, 0, stream>>>(ei, bh, E, NB);
  bscan_k<<<1, 1024, 0, stream>>>(bh, bbase, NB);
  bpartC_k<<<ebC, 256, 0, stream>>>(ei, bbase, bcur, ebuf, E, NB);
  bbuildD_k<<<NB, 256, 0, stream>>>(ebuf, bh, bbase, rp, cnt, dis, csr, N);
  dhist_k<<<nb256, 256, 0, stream>>>(cnt, dh, N);
  dscan_k<<<1, 256, 0, stream>>>(dh, dbase);
  dperm_k<<<nb256, 256, 0, stream>>>(cnt, rp, dis, dbase, dcur, prc, N);
  build_feats_k<<<nb256, 256, 0, stream>>>(x, semb, nemb, dis, feats16, N);

  int gemmb = ceil_div(N, 128);

  // layer 1: agg18 on bf16 -> gemm18 -> hb16
  agg18b_k<<<ceil_div(N, 16), 256, 0, stream>>>(feats16, prc, csr, agg1, N);
  gemm18_k<<<ceil_div(N, 8), 256, 0, stream>>>(agg1, W1, b1, dis, hb16, N);
  // layer 2: bf16 gather -> A_hi/A_lo -> MFMA gemm -> hb16
  agg128b_k<<<ceil_div(N, 4), 256, 0, stream>>>(hb16, prc, csr, Ahi, Alo, N);
  gemm128m_k<0><<<gemmb, 256, 0, stream>>>(Ahi, Alo, w2thi, w2tlo, b2, dis,
                                           nullptr, (unsigned short*)hb16, N);
  // layer 3: bf16 gather -> A_hi/A_lo -> MFMA gemm -> fp32 h3
  agg128b_k<<<ceil_div(N, 4), 256, 0, stream>>>(hb16, prc, csr, Ahi, Alo, N);
  gemm128m_k<1><<<gemmb, 256, 0, stream>>>(Ahi, Alo, w3thi, w3tlo, b3, dis,
                                           bufA, nullptr, N);   // bufA = h3

  // graph offsets + decoder
  ghist_k<<<nb256, 256, 0, stream>>>(batch, gc, N);
  gscan_k<<<1, 1024, 0, stream>>>(gc, go, G);
  gather_k<<<G, H, 0, stream>>>(bufA, go, gap, ginp, ghf, ghb, G);

  int gb = ceil_div(G, GPB);
  for (int t = 0; t < GAPLEN; ++t){
    gru_step_k<<<dim3(gb, 2), 256, 0, stream>>>(ginp, ghf, ghb,
                                                Wih_f, Whh_f, bih_f, bhh_f,
                                                Wih_b, Whh_b, bih_b, bhh_b, G);
    post_step_k<<<gb, 256, 0, stream>>>(ghf, ghb, Wred, bred, Wh1, bh1, Wh2, bh2,
                                        ginp, out, G, t);
  }
}